// Round 16
// baseline (181.420 us; speedup 1.0000x reference)
//
#include <hip/hip_runtime.h>

// ---------------------------------------------------------------------------
// CrossGraphNodeAttention: out = softmax(mask(Q K^T / 16)) V per batch
//   Q = A@Wq^T+bq, K = B@Wk^T+bk, V = B@Wv^T+bv;  B=8, N=2048, H=256
// Round 16: combine fused into attn via last-finisher (device-scope
// threadfence + atomicAdd on 128 per-(b,qt) counters, zeroed by wprep each
// launch). All splits of a (b,qt) group are batch->XCD pinned, so the
// finisher's Opart reads are same-XCD L2 hits. Output = pure function of
// all splits -> deterministic. proj: W-stage issued before X prologue
// (overlaps cold-HBM X latency). attn core frozen at r13 (47.2us).
// ---------------------------------------------------------------------------

typedef __attribute__((ext_vector_type(8))) __bf16 bf16x8;
typedef __attribute__((ext_vector_type(4))) __bf16 bf16x4;
typedef __attribute__((ext_vector_type(4))) float f32x4;

#if __has_builtin(__builtin_amdgcn_exp2f)
#define EXP2(x) __builtin_amdgcn_exp2f(x)
#else
#define EXP2(x) exp2f(x)
#endif

#define MFMA16(a, b, c) __builtin_amdgcn_mfma_f32_16x16x32_bf16((a), (b), (c), 0, 0, 0)

typedef const __attribute__((address_space(1))) char gas_char;
typedef __attribute__((address_space(3))) char las_char;

// global -> LDS direct copy: 16B/lane, LDS dest = uniform base (+lane*16 HW).
static __device__ __forceinline__ void gload16(const void* g, void* l) {
  __builtin_amdgcn_global_load_lds((gas_char*)g, (las_char*)l, 16, 0, 0);
}

static __device__ __forceinline__ bf16x8 pack8(f32x4 a, f32x4 b) {
  bf16x8 r;
  r[0] = (__bf16)a[0]; r[1] = (__bf16)a[1]; r[2] = (__bf16)a[2]; r[3] = (__bf16)a[3];
  r[4] = (__bf16)b[0]; r[5] = (__bf16)b[1]; r[6] = (__bf16)b[2]; r[7] = (__bf16)b[3];
  return r;
}

// ---------------------------------------------------------------------------
// wprep: blocks 0..95 convert W (f32 -> bf16, pre-swizzled quarter layout,
// Wq scaled by log2e/16); blocks 96..159 build mask bias + zero counters.
// ---------------------------------------------------------------------------
__global__ __launch_bounds__(256) void wprep_kernel(
    const float* __restrict__ Wq, const float* __restrict__ Wk,
    const float* __restrict__ Wv, const int* __restrict__ mask,
    __bf16* __restrict__ Wb, float* __restrict__ mb, int* __restrict__ cnt) {
  const int bid = blockIdx.x;
  if (bid < 96) {
    int c = bid * 256 + threadIdx.x;  // chunk id, 8192 chunks per W
    int w_id = c >> 13;
    int j = c & 8191;
    const float* __restrict__ W = (w_id == 0) ? Wq : (w_id == 1 ? Wk : Wv);
    int n = j >> 5;
    int c5 = j & 31;
    int qtr = c5 >> 3;
    int k8 = (c5 & 7) << 3;
    const float* wp = &W[n * 256 + qtr * 64 + k8];
    f32x4 w0 = *(const f32x4*)wp;
    f32x4 w1 = *(const f32x4*)(wp + 4);
    if (w_id == 0) {
      const float cs = 0.090168440f;  // log2(e)/16
      w0[0] *= cs; w0[1] *= cs; w0[2] *= cs; w0[3] *= cs;
      w1[0] *= cs; w1[1] *= cs; w1[2] *= cs; w1[3] *= cs;
    }
    int kx = k8 ^ ((n & 7) << 3);
    *(bf16x8*)&Wb[(size_t)w_id * 65536 + qtr * 16384 + n * 64 + kx] =
        pack8(w0, w1);
  } else {
    int i = (bid - 96) * 256 + threadIdx.x;
    if (i < 8 * 2048) mb[i] = (mask[i] != 0) ? 0.0f : -1.0e30f;
    if (i < 128) cnt[i] = 0;  // re-zeroed every launch (graph-replay safe)
  }
}

// ---------------------------------------------------------------------------
// Projection v4b: grid 512. pid<256: Q row-group (A, Wq). pid>=256: fused
// K+V row-group (B read once, Wk+Wv interleaved chunks). W chunk 0 staged
// BEFORE the X prologue so cold-HBM X latency overlaps staging.
// ---------------------------------------------------------------------------
__global__ __launch_bounds__(256, 2) void proj_kernel(
    const float* __restrict__ A, const float* __restrict__ Bm,
    const __bf16* __restrict__ Wb,
    const float* __restrict__ bq, const float* __restrict__ bk,
    const float* __restrict__ bv,
    __bf16* __restrict__ QF, __bf16* __restrict__ KF, __bf16* __restrict__ VF) {
  extern __shared__ char smem[];  // 2 x 32KB W chunk buffers
  const int pid = blockIdx.x;
  const bool isQ = (pid < 256);
  const int rb = (pid & 255) << 6;  // row base in flattened [16384]
  const float* __restrict__ X = isQ ? A : Bm;
  const int tid = threadIdx.x;
  const int w = tid >> 6, l = tid & 63, lo = l & 15, g = l >> 4;
  const int r0 = rb + w * 16;

  #define STAGEW(srcbase, buf)                                                \
    {                                                                         \
      const char* gw = (srcbase) + w * 1024 + l * 16;                         \
      char* lw = smem + (buf)*32768 + w * 1024;                               \
      gload16(gw, lw);                                                        \
      gload16(gw + 4096, lw + 4096);                                          \
      gload16(gw + 8192, lw + 8192);                                          \
      gload16(gw + 12288, lw + 12288);                                        \
      gload16(gw + 16384, lw + 16384);                                        \
      gload16(gw + 20480, lw + 20480);                                        \
      gload16(gw + 24576, lw + 24576);                                        \
      gload16(gw + 28672, lw + 28672);                                        \
    }

  const char* Wq_ = (const char*)Wb;
  const char* Wk_ = (const char*)(Wb + 65536);
  const char* Wv_ = (const char*)(Wb + 131072);

  // issue W chunk 0 first; X loads' HBM latency overlaps it
  if (isQ) {
    STAGEW(Wq_, 0);
  } else {
    STAGEW(Wk_, 0);
  }

  // X prologue: 8 chunks (qtr*2+ks2), 32B f32 each -> bf16x8 regs
  bf16x8 xf[8];
#pragma unroll
  for (int q8 = 0; q8 < 8; ++q8) {
    const float* xp = &X[(r0 + lo) * 256 + q8 * 32 + g * 8];
    xf[q8] = pack8(*(const f32x4*)xp, *(const f32x4*)(xp + 4));
  }
  __syncthreads();  // W chunk 0 + X loads drained

  if (isQ) {
    f32x4 acc[16];
#pragma unroll
    for (int j = 0; j < 16; ++j) acc[j] = (f32x4){0.f, 0.f, 0.f, 0.f};
    for (int qtr = 0; qtr < 4; ++qtr) {
      const int cur = qtr & 1;
      if (qtr < 3) STAGEW(Wq_ + (qtr + 1) * 32768, cur ^ 1);
      const __bf16* Wl = (const __bf16*)(smem + cur * 32768);
#pragma unroll
      for (int ks2 = 0; ks2 < 2; ++ks2) {
        bf16x8 xcur = xf[qtr * 2 + ks2];
#pragma unroll
        for (int nt = 0; nt < 16; ++nt) {
          int n = nt * 16 + lo;
          int kchunk = (ks2 * 4 + g) ^ (n & 7);
          bf16x8 wf = *(const bf16x8*)&Wl[n * 64 + kchunk * 8];
          acc[nt] = MFMA16(xcur, wf, acc[nt]);
        }
      }
      __syncthreads();
    }
    const float cs = 0.090168440f;
    const size_t rgbase = (size_t)(r0 >> 4) << 12;
#pragma unroll
    for (int nt = 0; nt < 16; ++nt) {
      int h = nt * 16 + lo;
      float bb = bq[h] * cs;
      size_t hpart = (size_t)((h >> 5) << 9) + (((h >> 3) & 3) << 7) + (h & 7);
#pragma unroll
      for (int r = 0; r < 4; ++r) {
        int R = r0 + g * 4 + r;
        QF[rgbase + hpart + ((R & 15) << 3)] = (__bf16)(acc[nt][r] + bb);
      }
    }
  } else {
    f32x4 accK[16], accV[16];
#pragma unroll
    for (int j = 0; j < 16; ++j) {
      accK[j] = (f32x4){0.f, 0.f, 0.f, 0.f};
      accV[j] = (f32x4){0.f, 0.f, 0.f, 0.f};
    }
    for (int c = 0; c < 8; ++c) {
      const int cur = c & 1;
      if (c < 7) {
        const int cn = c + 1;
        const char* src = ((cn & 1) ? Wv_ : Wk_) + (cn >> 1) * 32768;
        STAGEW(src, cur ^ 1);
      }
      const __bf16* Wl = (const __bf16*)(smem + cur * 32768);
      const int qtr = c >> 1;
#pragma unroll
      for (int ks2 = 0; ks2 < 2; ++ks2) {
        bf16x8 xcur = xf[qtr * 2 + ks2];
#pragma unroll
        for (int nt = 0; nt < 16; ++nt) {
          int n = nt * 16 + lo;
          int kchunk = (ks2 * 4 + g) ^ (n & 7);
          bf16x8 wf = *(const bf16x8*)&Wl[n * 64 + kchunk * 8];
          if (c & 1) {
            accV[nt] = MFMA16(wf, xcur, accV[nt]);
          } else {
            accK[nt] = MFMA16(xcur, wf, accK[nt]);
          }
        }
      }
      __syncthreads();
    }
    const size_t rgbase = (size_t)(r0 >> 4) << 12;
#pragma unroll
    for (int nt = 0; nt < 16; ++nt) {
      int h = nt * 16 + lo;
      float bb = bk[h];
      size_t hpart = (size_t)((h >> 5) << 9) + (((h >> 3) & 3) << 7) + (h & 7);
#pragma unroll
      for (int r = 0; r < 4; ++r) {
        int R = r0 + g * 4 + r;
        KF[rgbase + hpart + ((R & 15) << 3)] = (__bf16)(accK[nt][r] + bb);
      }
    }
    const int bidx = r0 >> 11;
    const int nb = r0 & 2047;
    __bf16* __restrict__ Vo = VF + (size_t)bidx * 524288;
#pragma unroll
    for (int ht = 0; ht < 16; ++ht)
#pragma unroll
      for (int r = 0; r < 4; ++r) {
        int h = ht * 16 + g * 4 + r;
        int n = nb + lo;
        Vo[((size_t)(n >> 6) << 14) + ((h >> 4) << 10) + (((n >> 3) & 7) << 7) +
           ((h & 15) << 3) + (n & 7)] = (__bf16)(accV[ht][r] + bv[h]);
      }
  }
}

// ---------------------------------------------------------------------------
// Attention: r13 core (QBLK=128, KVBLK=32, 2 blocks/CU, counted vmcnt,
// max-free softmax, bf16 Opart) + fused last-finisher combine.
// ---------------------------------------------------------------------------
__global__ __launch_bounds__(256, 2) void attn_kernel(
    const __bf16* __restrict__ QF, const __bf16* __restrict__ KF,
    const __bf16* __restrict__ VF, const float* __restrict__ mb,
    __bf16* __restrict__ Opart, float* __restrict__ lpart,
    int* __restrict__ cnt, float* __restrict__ out, int chunk, int direct) {
  extern __shared__ char smem[];  // [K 2x16K][V 2x16K][P 4x2560][mbl 2K][flag]
  const int bid = blockIdx.x;
  const int b = bid & 7;            // batch -> XCD pinning
  const int rest = bid >> 3;
  const int qt = rest & 15;
  const int s = rest >> 4;
  const int tid = threadIdx.x;
  const int w = tid >> 6, l = tid & 63, lo = l & 15, g = l >> 4;
  const int q0 = qt * 128 + w * 32;
  const __bf16* __restrict__ Qb = QF + ((size_t)b * 2048 + q0) * 256;
  const __bf16* __restrict__ Kb = KF + (size_t)b * 2048 * 256;
  const __bf16* __restrict__ Vb = VF + (size_t)b * 524288;
  const float* __restrict__ mbb = mb + b * 2048;
  __bf16* Pw = (__bf16*)(smem + 65536) + w * 1280;  // stride-40 rows
  float* mbl = (float*)(smem + 75776);              // chunk<=512 floats
  volatile int* lastflag = (volatile int*)(smem + 77824);

  bf16x8 qf[2][8];  // 2 q-row-tiles, x32 B-operand frags
#pragma unroll
  for (int u = 0; u < 2; ++u)
#pragma unroll
    for (int hs = 0; hs < 8; ++hs)
      qf[u][hs] = *(const bf16x8*)&Qb[u * 4096 + hs * 512 + l * 8];

  f32x4 oacc[2][16];
#pragma unroll
  for (int u = 0; u < 2; ++u)
#pragma unroll
    for (int i = 0; i < 16; ++i) oacc[u][i] = (f32x4){0.f, 0.f, 0.f, 0.f};
  float lsum[2] = {0.f, 0.f};

  const int kv0 = s * chunk;
  const int niter = chunk >> 5;

  #define STAGE_K(kvb, buf)                                                   \
    {                                                                         \
      const char* gk = (const char*)(Kb + (size_t)(kvb) * 256) + w * 4096 +   \
                       l * 16;                                                \
      char* lk = smem + (buf)*16384 + w * 4096;                               \
      gload16(gk, lk);                                                        \
      gload16(gk + 1024, lk + 1024);                                          \
      gload16(gk + 2048, lk + 2048);                                          \
      gload16(gk + 3072, lk + 3072);                                          \
    }
  #define STAGE_V(kvb, buf)                                                   \
    {                                                                         \
      const char* gv = (const char*)(Vb + (((size_t)(kvb) >> 6) << 14) +      \
                                     (((kvb) >> 5) & 1) * 512) +              \
                       w * 8192 + l * 16;                                     \
      char* lv = smem + 32768 + (buf)*16384 + w * 4096;                       \
      gload16(gv, lv);                                                        \
      gload16(gv + 2048, lv + 1024);                                          \
      gload16(gv + 4096, lv + 2048);                                          \
      gload16(gv + 6144, lv + 3072);                                          \
    }

  if (!direct)
    for (int j = tid; j < chunk; j += 256) mbl[j] = mbb[kv0 + j];
  STAGE_K(kv0, 0);
  STAGE_V(kv0, 0);
  __syncthreads();  // full drain (prologue only)

  for (int it = 0; it < niter; ++it) {
    const int kvb = kv0 + (it << 5);
    const int cur = it & 1;
    const bool pre = (it + 1 < niter);
    if (pre) STAGE_K(kvb + 32, cur ^ 1);
    const char* kbase = smem + cur * 16384;
    const char* vbase = smem + 32768 + cur * 16384;

    // QK^T: each K frag feeds both q-tiles
    f32x4 sacc[2][2];
#pragma unroll
    for (int u = 0; u < 2; ++u)
#pragma unroll
      for (int t = 0; t < 2; ++t) sacc[u][t] = (f32x4){0.f, 0.f, 0.f, 0.f};
    __builtin_amdgcn_s_setprio(1);
#pragma unroll
    for (int t = 0; t < 2; ++t)
#pragma unroll
      for (int hs = 0; hs < 8; ++hs) {
        bf16x8 kf = *(const bf16x8*)(kbase + t * 8192 + hs * 1024 + l * 16);
        sacc[0][t] = MFMA16(kf, qf[0][hs], sacc[0][t]);
        sacc[1][t] = MFMA16(kf, qf[1][hs], sacc[1][t]);
      }
    __builtin_amdgcn_s_setprio(0);

    // max-free softmax: P = exp2(s + bias); masked lanes -> exactly 0.
    f32x4 bias4[2];
#pragma unroll
    for (int t = 0; t < 2; ++t) {
      if (direct)
        bias4[t] = *(const f32x4*)&mbb[kvb + t * 16 + g * 4];
      else
        bias4[t] = *(const f32x4*)&mbl[(it << 5) + t * 16 + g * 4];
    }
#pragma unroll
    for (int u = 0; u < 2; ++u)
#pragma unroll
      for (int t = 0; t < 2; ++t) {
        float p0 = EXP2(sacc[u][t][0] + bias4[t][0]);
        float p1 = EXP2(sacc[u][t][1] + bias4[t][1]);
        float p2 = EXP2(sacc[u][t][2] + bias4[t][2]);
        float p3 = EXP2(sacc[u][t][3] + bias4[t][3]);
        lsum[u] += (p0 + p1) + (p2 + p3);
        bf16x4 pk;
        pk[0] = (__bf16)p0; pk[1] = (__bf16)p1;
        pk[2] = (__bf16)p2; pk[3] = (__bf16)p3;
        *(bf16x4*)&Pw[u * 640 + lo * 40 + t * 16 + g * 4] = pk;
      }
    // P frags (same-wave LDS write->read)
    bf16x8 pf[2];
#pragma unroll
    for (int u = 0; u < 2; ++u)
      pf[u] = *(const bf16x8*)&Pw[u * 640 + lo * 40 + g * 8];

    // (A) V(i) retired (K(i+1) in flight); publish V(i) to all warps.
    if (direct || !pre) {
      asm volatile("s_waitcnt vmcnt(0)" ::: "memory");
    } else {
      asm volatile("s_waitcnt vmcnt(4)" ::: "memory");
    }
    __builtin_amdgcn_s_barrier();
    __builtin_amdgcn_sched_barrier(0);

    if (pre) STAGE_V(kvb + 32, cur ^ 1);

    // PV: each V frag feeds both q-tiles
    __builtin_amdgcn_s_setprio(1);
#pragma unroll
    for (int ht = 0; ht < 16; ++ht) {
      bf16x8 vf = *(const bf16x8*)(vbase + ht * 1024 + l * 16);
      oacc[0][ht] = MFMA16(vf, pf[0], oacc[0][ht]);
      oacc[1][ht] = MFMA16(vf, pf[1], oacc[1][ht]);
    }
    __builtin_amdgcn_s_setprio(0);

    // (B) K(i+1) retired (V(i+1) in flight); publish K(i+1).
    if (direct || !pre) {
      asm volatile("s_waitcnt vmcnt(0)" ::: "memory");
    } else {
      asm volatile("s_waitcnt vmcnt(4)" ::: "memory");
    }
    __builtin_amdgcn_s_barrier();
    __builtin_amdgcn_sched_barrier(0);
  }

#pragma unroll
  for (int u = 0; u < 2; ++u) {
    float ls = lsum[u];
    ls += __shfl_xor(ls, 16);
    ls += __shfl_xor(ls, 32);
    const int q0u = q0 + u * 16;
    if (direct) {
      float inv = 1.0f / ls;
      float* __restrict__ Ob = out + ((size_t)b * 2048 + q0u) * 256;
#pragma unroll
      for (int ht = 0; ht < 16; ++ht) {
        f32x4 v = oacc[u][ht];
        v[0] *= inv; v[1] *= inv; v[2] *= inv; v[3] *= inv;
        *(f32x4*)&Ob[lo * 256 + ht * 16 + g * 4] = v;
      }
    } else {
      const size_t rowbase = (size_t)(s * 8 + b) * 2048 + q0u;
      __bf16* __restrict__ Ob = Opart + rowbase * 256;
#pragma unroll
      for (int ht = 0; ht < 16; ++ht) {
        f32x4 v = oacc[u][ht];
        bf16x4 pk;
        pk[0] = (__bf16)v[0]; pk[1] = (__bf16)v[1];
        pk[2] = (__bf16)v[2]; pk[3] = (__bf16)v[3];
        *(bf16x4*)&Ob[lo * 256 + ht * 16 + g * 4] = pk;
      }
      if (l < 16) lpart[rowbase + lo] = ls;
    }
  }

  // last-finisher combine: release -> count -> (acquire -> combine)
  if (!direct) {
    __threadfence();  // release: Opart/lpart visible device-wide
    if (tid == 0) {
      int old = atomicAdd(&cnt[b * 16 + qt], 1);
      *lastflag = (old == (2048 / chunk) - 1) ? 1 : 0;
    }
    __syncthreads();
    if (*lastflag) {
      __threadfence();  // acquire: other splits' writes visible
      const int nsplit = 2048 / chunk;
      // combine rows [b*2048 + qt*128, +128) across splits
      for (int uu = tid; uu < 128 * 64; uu += 256) {
        int j = uu >> 6;           // row within group
        int h4 = (uu & 63) << 2;
        f32x4 acc = (f32x4){0.f, 0.f, 0.f, 0.f};
        float denom = 0.f;
        for (int s2 = 0; s2 < nsplit; ++s2) {
          size_t row = (size_t)(s2 * 8 + b) * 2048 + qt * 128 + j;
          denom += lpart[row];
          bf16x4 o = *(const bf16x4*)&Opart[row * 256 + h4];
          acc[0] += (float)o[0]; acc[1] += (float)o[1];
          acc[2] += (float)o[2]; acc[3] += (float)o[3];
        }
        float inv = 1.0f / denom;
        f32x4 r;
        r[0] = acc[0] * inv; r[1] = acc[1] * inv;
        r[2] = acc[2] * inv; r[3] = acc[3] * inv;
        *(f32x4*)&out[((size_t)b * 2048 + qt * 128 + j) * 256 + h4] = r;
      }
    }
  }
}

// ---------------------------------------------------------------------------
extern "C" void kernel_launch(void* const* d_in, const int* in_sizes, int n_in,
                              void* d_out, int out_size, void* d_ws, size_t ws_size,
                              hipStream_t stream) {
  const float* A = (const float*)d_in[0];
  const float* B = (const float*)d_in[1];
  const int* mask = (const int*)d_in[2];
  const float* Wq = (const float*)d_in[3];
  const float* bq = (const float*)d_in[4];
  const float* Wk = (const float*)d_in[5];
  const float* bk = (const float*)d_in[6];
  const float* Wv = (const float*)d_in[7];
  const float* bv = (const float*)d_in[8];

  char* ws = (char*)d_ws;
  __bf16* QF = (__bf16*)(ws);                         // 8 MB
  __bf16* KF = (__bf16*)(ws + (8ull << 20));          // 8 MB
  __bf16* VF = (__bf16*)(ws + (16ull << 20));         // 8 MB
  float* mb = (float*)(ws + (24ull << 20));           // 64 KB
  float* lpart = (float*)(ws + (24ull << 20) + 0x10000);   // <=512 KB
  __bf16* Wb = (__bf16*)(ws + (24ull << 20) + 0x90000);    // 384 KB
  int* cnt = (int*)(ws + (24ull << 20) + 0xF0000);         // 512 B
  __bf16* Opart = (__bf16*)(ws + (25ull << 20));           // S * 8 MB (bf16)

  const size_t base = 25ull << 20;
  const size_t part = 8ull << 20;
  int S;
  if (ws_size >= base + 4 * part) S = 4;
  else if (ws_size >= base + 2 * part) S = 2;
  else if (ws_size >= base + 1 * part) S = 1;
  else S = 0;  // direct mode (no split)

  const int PSMEM = 65536;  // proj: 2 x 32KB W chunk dbuf
  (void)hipFuncSetAttribute((const void*)proj_kernel,
                            hipFuncAttributeMaxDynamicSharedMemorySize, PSMEM);
  const int SMEM = 65536 + 4 * 1280 * 2 + 2048 + 64;  // 77888 B -> 2 blocks/CU
  (void)hipFuncSetAttribute((const void*)attn_kernel,
                            hipFuncAttributeMaxDynamicSharedMemorySize, SMEM);

  wprep_kernel<<<160, 256, 0, stream>>>(Wq, Wk, Wv, mask, Wb, mb, cnt);
  proj_kernel<<<512, 256, PSMEM, stream>>>(A, B, Wb, bq, bk, bv, QF, KF, VF);
  if (S == 0) {
    attn_kernel<<<128, 256, SMEM, stream>>>(QF, KF, VF, mb, nullptr, nullptr,
                                            cnt, (float*)d_out, 2048, 1);
  } else {
    attn_kernel<<<128 * S, 256, SMEM, stream>>>(QF, KF, VF, mb, Opart, lpart,
                                                cnt, (float*)d_out, 2048 / S, 0);
  }
}

// Round 17
// 83.704 us; speedup vs baseline: 2.1674x; 2.1674x over previous
//
#include <hip/hip_runtime.h>

// ---------------------------------------------------------------------------
// CrossGraphNodeAttention: out = softmax(mask(Q K^T / 16)) V per batch
//   Q = A@Wq^T+bq, K = B@Wk^T+bk, V = B@Wv^T+bv;  B=8, N=2048, H=256
// Round 17: revert r16's fused-combine (threadfence L2-writeback collapse:
// attn 47->153us). Back to r15 verified structure (83.3us) + one free tweak
// kept from r16: proj stages W chunk 0 BEFORE the X prologue (issue-early,
// X HBM latency overlaps staging). Separate combine kernel restored.
// attn frozen at r13 core (47.2us).
// ---------------------------------------------------------------------------

typedef __attribute__((ext_vector_type(8))) __bf16 bf16x8;
typedef __attribute__((ext_vector_type(4))) __bf16 bf16x4;
typedef __attribute__((ext_vector_type(4))) float f32x4;

#if __has_builtin(__builtin_amdgcn_exp2f)
#define EXP2(x) __builtin_amdgcn_exp2f(x)
#else
#define EXP2(x) exp2f(x)
#endif

#define MFMA16(a, b, c) __builtin_amdgcn_mfma_f32_16x16x32_bf16((a), (b), (c), 0, 0, 0)

typedef const __attribute__((address_space(1))) char gas_char;
typedef __attribute__((address_space(3))) char las_char;

// global -> LDS direct copy: 16B/lane, LDS dest = uniform base (+lane*16 HW).
static __device__ __forceinline__ void gload16(const void* g, void* l) {
  __builtin_amdgcn_global_load_lds((gas_char*)g, (las_char*)l, 16, 0, 0);
}

static __device__ __forceinline__ bf16x8 pack8(f32x4 a, f32x4 b) {
  bf16x8 r;
  r[0] = (__bf16)a[0]; r[1] = (__bf16)a[1]; r[2] = (__bf16)a[2]; r[3] = (__bf16)a[3];
  r[4] = (__bf16)b[0]; r[5] = (__bf16)b[1]; r[6] = (__bf16)b[2]; r[7] = (__bf16)b[3];
  return r;
}

// ---------------------------------------------------------------------------
// wprep: blocks 0..95 convert W (f32 -> bf16, pre-swizzled quarter layout,
// Wq scaled by log2e/16); blocks 96..159 build the mask bias.
// ---------------------------------------------------------------------------
__global__ __launch_bounds__(256) void wprep_kernel(
    const float* __restrict__ Wq, const float* __restrict__ Wk,
    const float* __restrict__ Wv, const int* __restrict__ mask,
    __bf16* __restrict__ Wb, float* __restrict__ mb) {
  const int bid = blockIdx.x;
  if (bid < 96) {
    int c = bid * 256 + threadIdx.x;  // chunk id, 8192 chunks per W
    int w_id = c >> 13;
    int j = c & 8191;
    const float* __restrict__ W = (w_id == 0) ? Wq : (w_id == 1 ? Wk : Wv);
    int n = j >> 5;
    int c5 = j & 31;
    int qtr = c5 >> 3;
    int k8 = (c5 & 7) << 3;
    const float* wp = &W[n * 256 + qtr * 64 + k8];
    f32x4 w0 = *(const f32x4*)wp;
    f32x4 w1 = *(const f32x4*)(wp + 4);
    if (w_id == 0) {
      const float cs = 0.090168440f;  // log2(e)/16
      w0[0] *= cs; w0[1] *= cs; w0[2] *= cs; w0[3] *= cs;
      w1[0] *= cs; w1[1] *= cs; w1[2] *= cs; w1[3] *= cs;
    }
    int kx = k8 ^ ((n & 7) << 3);
    *(bf16x8*)&Wb[(size_t)w_id * 65536 + qtr * 16384 + n * 64 + kx] =
        pack8(w0, w1);
  } else {
    int i = (bid - 96) * 256 + threadIdx.x;
    if (i < 8 * 2048) mb[i] = (mask[i] != 0) ? 0.0f : -1.0e30f;
  }
}

// ---------------------------------------------------------------------------
// Projection v4b: grid 512. pid<256: Q row-group (A, Wq). pid>=256: fused
// K+V row-group (B read once, Wk+Wv interleaved chunks). W chunk 0 staged
// BEFORE the X prologue (issue-early). W chunks double-buffered 2x32KB.
// ---------------------------------------------------------------------------
__global__ __launch_bounds__(256, 2) void proj_kernel(
    const float* __restrict__ A, const float* __restrict__ Bm,
    const __bf16* __restrict__ Wb,
    const float* __restrict__ bq, const float* __restrict__ bk,
    const float* __restrict__ bv,
    __bf16* __restrict__ QF, __bf16* __restrict__ KF, __bf16* __restrict__ VF) {
  extern __shared__ char smem[];  // 2 x 32KB W chunk buffers
  const int pid = blockIdx.x;
  const bool isQ = (pid < 256);
  const int rb = (pid & 255) << 6;  // row base in flattened [16384]
  const float* __restrict__ X = isQ ? A : Bm;
  const int tid = threadIdx.x;
  const int w = tid >> 6, l = tid & 63, lo = l & 15, g = l >> 4;
  const int r0 = rb + w * 16;

  #define STAGEW(srcbase, buf)                                                \
    {                                                                         \
      const char* gw = (srcbase) + w * 1024 + l * 16;                         \
      char* lw = smem + (buf)*32768 + w * 1024;                               \
      gload16(gw, lw);                                                        \
      gload16(gw + 4096, lw + 4096);                                          \
      gload16(gw + 8192, lw + 8192);                                          \
      gload16(gw + 12288, lw + 12288);                                        \
      gload16(gw + 16384, lw + 16384);                                        \
      gload16(gw + 20480, lw + 20480);                                        \
      gload16(gw + 24576, lw + 24576);                                        \
      gload16(gw + 28672, lw + 28672);                                        \
    }

  const char* Wq_ = (const char*)Wb;
  const char* Wk_ = (const char*)(Wb + 65536);
  const char* Wv_ = (const char*)(Wb + 131072);

  // issue W chunk 0 first; X loads' HBM latency overlaps it
  if (isQ) {
    STAGEW(Wq_, 0);
  } else {
    STAGEW(Wk_, 0);
  }

  // X prologue: 8 chunks (qtr*2+ks2), 32B f32 each -> bf16x8 regs
  bf16x8 xf[8];
#pragma unroll
  for (int q8 = 0; q8 < 8; ++q8) {
    const float* xp = &X[(r0 + lo) * 256 + q8 * 32 + g * 8];
    xf[q8] = pack8(*(const f32x4*)xp, *(const f32x4*)(xp + 4));
  }
  __syncthreads();  // W chunk 0 + X loads drained

  if (isQ) {
    f32x4 acc[16];
#pragma unroll
    for (int j = 0; j < 16; ++j) acc[j] = (f32x4){0.f, 0.f, 0.f, 0.f};
    for (int qtr = 0; qtr < 4; ++qtr) {
      const int cur = qtr & 1;
      if (qtr < 3) STAGEW(Wq_ + (qtr + 1) * 32768, cur ^ 1);
      const __bf16* Wl = (const __bf16*)(smem + cur * 32768);
#pragma unroll
      for (int ks2 = 0; ks2 < 2; ++ks2) {
        bf16x8 xcur = xf[qtr * 2 + ks2];
#pragma unroll
        for (int nt = 0; nt < 16; ++nt) {
          int n = nt * 16 + lo;
          int kchunk = (ks2 * 4 + g) ^ (n & 7);
          bf16x8 wf = *(const bf16x8*)&Wl[n * 64 + kchunk * 8];
          acc[nt] = MFMA16(xcur, wf, acc[nt]);
        }
      }
      __syncthreads();
    }
    const float cs = 0.090168440f;
    const size_t rgbase = (size_t)(r0 >> 4) << 12;
#pragma unroll
    for (int nt = 0; nt < 16; ++nt) {
      int h = nt * 16 + lo;
      float bb = bq[h] * cs;
      size_t hpart = (size_t)((h >> 5) << 9) + (((h >> 3) & 3) << 7) + (h & 7);
#pragma unroll
      for (int r = 0; r < 4; ++r) {
        int R = r0 + g * 4 + r;
        QF[rgbase + hpart + ((R & 15) << 3)] = (__bf16)(acc[nt][r] + bb);
      }
    }
  } else {
    f32x4 accK[16], accV[16];
#pragma unroll
    for (int j = 0; j < 16; ++j) {
      accK[j] = (f32x4){0.f, 0.f, 0.f, 0.f};
      accV[j] = (f32x4){0.f, 0.f, 0.f, 0.f};
    }
    for (int c = 0; c < 8; ++c) {
      const int cur = c & 1;
      if (c < 7) {
        const int cn = c + 1;
        const char* src = ((cn & 1) ? Wv_ : Wk_) + (cn >> 1) * 32768;
        STAGEW(src, cur ^ 1);
      }
      const __bf16* Wl = (const __bf16*)(smem + cur * 32768);
      const int qtr = c >> 1;
#pragma unroll
      for (int ks2 = 0; ks2 < 2; ++ks2) {
        bf16x8 xcur = xf[qtr * 2 + ks2];
#pragma unroll
        for (int nt = 0; nt < 16; ++nt) {
          int n = nt * 16 + lo;
          int kchunk = (ks2 * 4 + g) ^ (n & 7);
          bf16x8 wf = *(const bf16x8*)&Wl[n * 64 + kchunk * 8];
          if (c & 1) {
            accV[nt] = MFMA16(wf, xcur, accV[nt]);
          } else {
            accK[nt] = MFMA16(xcur, wf, accK[nt]);
          }
        }
      }
      __syncthreads();
    }
    const size_t rgbase = (size_t)(r0 >> 4) << 12;
#pragma unroll
    for (int nt = 0; nt < 16; ++nt) {
      int h = nt * 16 + lo;
      float bb = bk[h];
      size_t hpart = (size_t)((h >> 5) << 9) + (((h >> 3) & 3) << 7) + (h & 7);
#pragma unroll
      for (int r = 0; r < 4; ++r) {
        int R = r0 + g * 4 + r;
        KF[rgbase + hpart + ((R & 15) << 3)] = (__bf16)(accK[nt][r] + bb);
      }
    }
    const int bidx = r0 >> 11;
    const int nb = r0 & 2047;
    __bf16* __restrict__ Vo = VF + (size_t)bidx * 524288;
#pragma unroll
    for (int ht = 0; ht < 16; ++ht)
#pragma unroll
      for (int r = 0; r < 4; ++r) {
        int h = ht * 16 + g * 4 + r;
        int n = nb + lo;
        Vo[((size_t)(n >> 6) << 14) + ((h >> 4) << 10) + (((n >> 3) & 7) << 7) +
           ((h & 15) << 3) + (n & 7)] = (__bf16)(accV[ht][r] + bv[h]);
      }
  }
}

// ---------------------------------------------------------------------------
// Attention (frozen r13 core): QBLK=128, KVBLK=32, 2 blocks/CU, counted
// vmcnt split-phase staging, max-free softmax, bf16 Opart.
// ---------------------------------------------------------------------------
__global__ __launch_bounds__(256, 2) void attn_kernel(
    const __bf16* __restrict__ QF, const __bf16* __restrict__ KF,
    const __bf16* __restrict__ VF, const float* __restrict__ mb,
    __bf16* __restrict__ Opart, float* __restrict__ lpart,
    float* __restrict__ out, int chunk, int direct) {
  extern __shared__ char smem[];  // [K 2x16K][V 2x16K][P 4x2560][mbl 2K]
  const int bid = blockIdx.x;
  const int b = bid & 7;            // batch -> XCD pinning
  const int rest = bid >> 3;
  const int qt = rest & 15;
  const int s = rest >> 4;
  const int tid = threadIdx.x;
  const int w = tid >> 6, l = tid & 63, lo = l & 15, g = l >> 4;
  const int q0 = qt * 128 + w * 32;
  const __bf16* __restrict__ Qb = QF + ((size_t)b * 2048 + q0) * 256;
  const __bf16* __restrict__ Kb = KF + (size_t)b * 2048 * 256;
  const __bf16* __restrict__ Vb = VF + (size_t)b * 524288;
  const float* __restrict__ mbb = mb + b * 2048;
  __bf16* Pw = (__bf16*)(smem + 65536) + w * 1280;  // stride-40 rows
  float* mbl = (float*)(smem + 75776);              // chunk<=512 floats

  bf16x8 qf[2][8];  // 2 q-row-tiles, x32 B-operand frags
#pragma unroll
  for (int u = 0; u < 2; ++u)
#pragma unroll
    for (int hs = 0; hs < 8; ++hs)
      qf[u][hs] = *(const bf16x8*)&Qb[u * 4096 + hs * 512 + l * 8];

  f32x4 oacc[2][16];
#pragma unroll
  for (int u = 0; u < 2; ++u)
#pragma unroll
    for (int i = 0; i < 16; ++i) oacc[u][i] = (f32x4){0.f, 0.f, 0.f, 0.f};
  float lsum[2] = {0.f, 0.f};

  const int kv0 = s * chunk;
  const int niter = chunk >> 5;

  #define STAGE_K(kvb, buf)                                                   \
    {                                                                         \
      const char* gk = (const char*)(Kb + (size_t)(kvb) * 256) + w * 4096 +   \
                       l * 16;                                                \
      char* lk = smem + (buf)*16384 + w * 4096;                               \
      gload16(gk, lk);                                                        \
      gload16(gk + 1024, lk + 1024);                                          \
      gload16(gk + 2048, lk + 2048);                                          \
      gload16(gk + 3072, lk + 3072);                                          \
    }
  #define STAGE_V(kvb, buf)                                                   \
    {                                                                         \
      const char* gv = (const char*)(Vb + (((size_t)(kvb) >> 6) << 14) +      \
                                     (((kvb) >> 5) & 1) * 512) +              \
                       w * 8192 + l * 16;                                     \
      char* lv = smem + 32768 + (buf)*16384 + w * 4096;                       \
      gload16(gv, lv);                                                        \
      gload16(gv + 2048, lv + 1024);                                          \
      gload16(gv + 4096, lv + 2048);                                          \
      gload16(gv + 6144, lv + 3072);                                          \
    }

  if (!direct)
    for (int j = tid; j < chunk; j += 256) mbl[j] = mbb[kv0 + j];
  STAGE_K(kv0, 0);
  STAGE_V(kv0, 0);
  __syncthreads();  // full drain (prologue only)

  for (int it = 0; it < niter; ++it) {
    const int kvb = kv0 + (it << 5);
    const int cur = it & 1;
    const bool pre = (it + 1 < niter);
    if (pre) STAGE_K(kvb + 32, cur ^ 1);
    const char* kbase = smem + cur * 16384;
    const char* vbase = smem + 32768 + cur * 16384;

    // QK^T: each K frag feeds both q-tiles
    f32x4 sacc[2][2];
#pragma unroll
    for (int u = 0; u < 2; ++u)
#pragma unroll
      for (int t = 0; t < 2; ++t) sacc[u][t] = (f32x4){0.f, 0.f, 0.f, 0.f};
    __builtin_amdgcn_s_setprio(1);
#pragma unroll
    for (int t = 0; t < 2; ++t)
#pragma unroll
      for (int hs = 0; hs < 8; ++hs) {
        bf16x8 kf = *(const bf16x8*)(kbase + t * 8192 + hs * 1024 + l * 16);
        sacc[0][t] = MFMA16(kf, qf[0][hs], sacc[0][t]);
        sacc[1][t] = MFMA16(kf, qf[1][hs], sacc[1][t]);
      }
    __builtin_amdgcn_s_setprio(0);

    // max-free softmax: P = exp2(s + bias); masked lanes -> exactly 0.
    f32x4 bias4[2];
#pragma unroll
    for (int t = 0; t < 2; ++t) {
      if (direct)
        bias4[t] = *(const f32x4*)&mbb[kvb + t * 16 + g * 4];
      else
        bias4[t] = *(const f32x4*)&mbl[(it << 5) + t * 16 + g * 4];
    }
#pragma unroll
    for (int u = 0; u < 2; ++u)
#pragma unroll
      for (int t = 0; t < 2; ++t) {
        float p0 = EXP2(sacc[u][t][0] + bias4[t][0]);
        float p1 = EXP2(sacc[u][t][1] + bias4[t][1]);
        float p2 = EXP2(sacc[u][t][2] + bias4[t][2]);
        float p3 = EXP2(sacc[u][t][3] + bias4[t][3]);
        lsum[u] += (p0 + p1) + (p2 + p3);
        bf16x4 pk;
        pk[0] = (__bf16)p0; pk[1] = (__bf16)p1;
        pk[2] = (__bf16)p2; pk[3] = (__bf16)p3;
        *(bf16x4*)&Pw[u * 640 + lo * 40 + t * 16 + g * 4] = pk;
      }
    // P frags (same-wave LDS write->read)
    bf16x8 pf[2];
#pragma unroll
    for (int u = 0; u < 2; ++u)
      pf[u] = *(const bf16x8*)&Pw[u * 640 + lo * 40 + g * 8];

    // (A) V(i) retired (K(i+1) in flight); publish V(i) to all warps.
    if (direct || !pre) {
      asm volatile("s_waitcnt vmcnt(0)" ::: "memory");
    } else {
      asm volatile("s_waitcnt vmcnt(4)" ::: "memory");
    }
    __builtin_amdgcn_s_barrier();
    __builtin_amdgcn_sched_barrier(0);

    if (pre) STAGE_V(kvb + 32, cur ^ 1);

    // PV: each V frag feeds both q-tiles
    __builtin_amdgcn_s_setprio(1);
#pragma unroll
    for (int ht = 0; ht < 16; ++ht) {
      bf16x8 vf = *(const bf16x8*)(vbase + ht * 1024 + l * 16);
      oacc[0][ht] = MFMA16(vf, pf[0], oacc[0][ht]);
      oacc[1][ht] = MFMA16(vf, pf[1], oacc[1][ht]);
    }
    __builtin_amdgcn_s_setprio(0);

    // (B) K(i+1) retired (V(i+1) in flight); publish K(i+1).
    if (direct || !pre) {
      asm volatile("s_waitcnt vmcnt(0)" ::: "memory");
    } else {
      asm volatile("s_waitcnt vmcnt(4)" ::: "memory");
    }
    __builtin_amdgcn_s_barrier();
    __builtin_amdgcn_sched_barrier(0);
  }

#pragma unroll
  for (int u = 0; u < 2; ++u) {
    float ls = lsum[u];
    ls += __shfl_xor(ls, 16);
    ls += __shfl_xor(ls, 32);
    const int q0u = q0 + u * 16;
    if (direct) {
      float inv = 1.0f / ls;
      float* __restrict__ Ob = out + ((size_t)b * 2048 + q0u) * 256;
#pragma unroll
      for (int ht = 0; ht < 16; ++ht) {
        f32x4 v = oacc[u][ht];
        v[0] *= inv; v[1] *= inv; v[2] *= inv; v[3] *= inv;
        *(f32x4*)&Ob[lo * 256 + ht * 16 + g * 4] = v;
      }
    } else {
      const size_t rowbase = (size_t)(s * 8 + b) * 2048 + q0u;
      __bf16* __restrict__ Ob = Opart + rowbase * 256;
#pragma unroll
      for (int ht = 0; ht < 16; ++ht) {
        f32x4 v = oacc[u][ht];
        bf16x4 pk;
        pk[0] = (__bf16)v[0]; pk[1] = (__bf16)v[1];
        pk[2] = (__bf16)v[2]; pk[3] = (__bf16)v[3];
        *(bf16x4*)&Ob[lo * 256 + ht * 16 + g * 4] = pk;
      }
      if (l < 16) lpart[rowbase + lo] = ls;
    }
  }
}

// ---------------------------------------------------------------------------
// Combine (max-free): out[row][h] = sum_s O_s[row][h] / sum_s l_s[row]
// ---------------------------------------------------------------------------
__global__ __launch_bounds__(256) void combine_kernel(
    const __bf16* __restrict__ Opart, const float* __restrict__ lpart,
    float* __restrict__ out, int nsplit) {
  int t = blockIdx.x * 256 + threadIdx.x;
  int row = t >> 6;
  int h4 = (t & 63) << 2;
  f32x4 acc = (f32x4){0.f, 0.f, 0.f, 0.f};
  float denom = 0.f;
  for (int s = 0; s < nsplit; ++s) {
    denom += lpart[s * 16384 + row];
    bf16x4 o = *(const bf16x4*)&Opart[((size_t)s * 16384 + row) * 256 + h4];
    acc[0] += (float)o[0]; acc[1] += (float)o[1];
    acc[2] += (float)o[2]; acc[3] += (float)o[3];
  }
  float inv = 1.0f / denom;
  f32x4 r;
  r[0] = acc[0] * inv; r[1] = acc[1] * inv;
  r[2] = acc[2] * inv; r[3] = acc[3] * inv;
  *(f32x4*)&out[(size_t)row * 256 + h4] = r;
}

// ---------------------------------------------------------------------------
extern "C" void kernel_launch(void* const* d_in, const int* in_sizes, int n_in,
                              void* d_out, int out_size, void* d_ws, size_t ws_size,
                              hipStream_t stream) {
  const float* A = (const float*)d_in[0];
  const float* B = (const float*)d_in[1];
  const int* mask = (const int*)d_in[2];
  const float* Wq = (const float*)d_in[3];
  const float* bq = (const float*)d_in[4];
  const float* Wk = (const float*)d_in[5];
  const float* bk = (const float*)d_in[6];
  const float* Wv = (const float*)d_in[7];
  const float* bv = (const float*)d_in[8];

  char* ws = (char*)d_ws;
  __bf16* QF = (__bf16*)(ws);                         // 8 MB
  __bf16* KF = (__bf16*)(ws + (8ull << 20));          // 8 MB
  __bf16* VF = (__bf16*)(ws + (16ull << 20));         // 8 MB
  float* mb = (float*)(ws + (24ull << 20));           // 64 KB
  float* lpart = (float*)(ws + (24ull << 20) + 0x10000);   // <=512 KB
  __bf16* Wb = (__bf16*)(ws + (24ull << 20) + 0x90000);    // 384 KB
  __bf16* Opart = (__bf16*)(ws + (25ull << 20));           // S * 8 MB (bf16)

  const size_t base = 25ull << 20;
  const size_t part = 8ull << 20;
  int S;
  if (ws_size >= base + 4 * part) S = 4;
  else if (ws_size >= base + 2 * part) S = 2;
  else if (ws_size >= base + 1 * part) S = 1;
  else S = 0;  // direct mode (no split)

  const int PSMEM = 65536;  // proj: 2 x 32KB W chunk dbuf
  (void)hipFuncSetAttribute((const void*)proj_kernel,
                            hipFuncAttributeMaxDynamicSharedMemorySize, PSMEM);
  const int SMEM = 65536 + 4 * 1280 * 2 + 2048;  // 77824 B -> 2 blocks/CU
  (void)hipFuncSetAttribute((const void*)attn_kernel,
                            hipFuncAttributeMaxDynamicSharedMemorySize, SMEM);

  wprep_kernel<<<160, 256, 0, stream>>>(Wq, Wk, Wv, mask, Wb, mb);
  proj_kernel<<<512, 256, PSMEM, stream>>>(A, B, Wb, bq, bk, bv, QF, KF, VF);
  if (S == 0) {
    attn_kernel<<<128, 256, SMEM, stream>>>(QF, KF, VF, mb, nullptr, nullptr,
                                            (float*)d_out, 2048, 1);
  } else {
    attn_kernel<<<128 * S, 256, SMEM, stream>>>(QF, KF, VF, mb, Opart, lpart,
                                                nullptr, 2048 / S, 0);
    combine_kernel<<<4096, 256, 0, stream>>>(Opart, lpart, (float*)d_out, S);
  }
}